// Round 1
// baseline (6043.821 us; speedup 1.0000x reference)
//
#include <hip/hip_runtime.h>
#include <stdint.h>

#define NNODES 100000
#define NEDGES 600000
#define NGRAPH 2048
#define DD 128
#define NLAYER 5
#define NPAD 100096   // 782*128

typedef __attribute__((ext_vector_type(8))) __bf16 bf16x8;
typedef __attribute__((ext_vector_type(4))) float f32x4;

__device__ __forceinline__ ushort f2b(float f) {
    union { float f; uint32_t u; } v; v.f = f;
    uint32_t r = v.u + 0x7FFFu + ((v.u >> 16) & 1u);
    return (ushort)(r >> 16);
}

__global__ void prep_w_kernel(const float* __restrict__ W1s, const float* __restrict__ W2s,
                              ushort* __restrict__ w1t, ushort* __restrict__ w2t) {
    int idx = blockIdx.x * 256 + threadIdx.x;
    const int per = 128 * 256;
    if (idx < NLAYER * per) {
        int i = idx / per, rem = idx % per;
        int n = rem >> 7, k = rem & 127;          // w1t[i][n(256)][k(128)] = W1s[i][k][n]
        w1t[idx] = f2b(W1s[(size_t)i * per + k * 256 + n]);
    } else if (idx < 2 * NLAYER * per) {
        int j = idx - NLAYER * per;
        int i = j / per, rem = j % per;
        int n = rem >> 8, k = rem & 255;          // w2t[i][n(128)][k(256)] = W2s[i][k][n]
        w2t[j] = f2b(W2s[(size_t)i * per + k * 128 + n]);
    }
}

__global__ void node_embed_kernel(const float* __restrict__ x, const float* __restrict__ W,
                                  const float* __restrict__ b, float* __restrict__ h) {
    int idx = blockIdx.x * 256 + threadIdx.x;
    if (idx >= NNODES * 128) return;
    int n = idx >> 7, d = idx & 127;
    float v = b[d];
#pragma unroll
    for (int k = 0; k < 9; ++k) v += x[n * 9 + k] * W[k * 128 + d];
    h[(size_t)n * 128 + d] = v;
}

__global__ void vn_init_kernel(const float* __restrict__ vne, float* __restrict__ vn) {
    int idx = blockIdx.x * 256 + threadIdx.x;
    if (idx >= NGRAPH * 128) return;
    vn[idx] = vne[idx & 127];
}

__global__ void scatter_add_kernel(const int* __restrict__ src, const int* __restrict__ dst,
                                   const float* __restrict__ h, float* __restrict__ agg) {
    int t = blockIdx.x * 256 + threadIdx.x;
    if (t >= NEDGES * 32) return;
    int e = t >> 5, j = t & 31;
    int s = src[e], d = dst[e];
    float4 v = ((const float4*)h)[(size_t)s * 32 + j];
    float* base = agg + (size_t)d * 128 + j * 4;
    atomicAdd(base + 0, v.x); atomicAdd(base + 1, v.y);
    atomicAdd(base + 2, v.z); atomicAdd(base + 3, v.w);
}

__global__ void add_convert_kernel(const float* __restrict__ h, const float* __restrict__ agg,
                                   ushort* __restrict__ xb) {
    int t = blockIdx.x * 256 + threadIdx.x;   // over NPAD*32 float4 units
    if (t >= NPAD * 32) return;
    int row = t >> 5;
    float4 o = make_float4(0.f, 0.f, 0.f, 0.f);
    if (row < NNODES) {
        float4 a = ((const float4*)h)[t];
        float4 g = ((const float4*)agg)[t];
        o = make_float4(a.x + g.x, a.y + g.y, a.z + g.z, a.w + g.w);
    }
    ushort4 u;
    u.x = f2b(o.x); u.y = f2b(o.y); u.z = f2b(o.z); u.w = f2b(o.w);
    ((ushort4*)xb)[t] = u;
}

// C = A[NPAD,K](bf16) @ BT^T  (BT is [NC,K] bf16, i.e. B transposed), +bias
// EPI 0: relu -> bf16 store to out_b [NPAD][NCtot]
// EPI 1: f32 store to out_f [NPAD][NCtot] + fused BN column sums (rows < NNODES)
template<int K, int EPI>
__global__ __launch_bounds__(256)
void gemm_kernel(const ushort* __restrict__ A, const ushort* __restrict__ BT,
                 const float* __restrict__ bias,
                 ushort* __restrict__ out_b, float* __restrict__ out_f,
                 float* __restrict__ stat_sum, float* __restrict__ stat_sq, int NCtot) {
    __shared__ __align__(16) ushort lA[4096];   // [q][row][8]
    __shared__ __align__(16) ushort lB[4096];   // [q][col][8]
    const int tid = threadIdx.x;
    const int lane = tid & 63, wid = tid >> 6;
    const int wr = wid >> 1, wc = wid & 1;
    const int rb = blockIdx.x * 128, cb = blockIdx.y * 128;
    const int q = lane >> 4, l16 = lane & 15;

    f32x4 acc[4][4] = {};

#pragma unroll
    for (int ks = 0; ks < K / 32; ++ks) {
        __syncthreads();
        {
            int c0 = tid, c1 = tid + 256;
            int r0 = c0 & 127, q0 = c0 >> 7;
            int r1 = c1 & 127, q1 = c1 >> 7;
            bf16x8 va0 = *(const bf16x8*)(A + (size_t)(rb + r0) * K + ks * 32 + q0 * 8);
            bf16x8 va1 = *(const bf16x8*)(A + (size_t)(rb + r1) * K + ks * 32 + q1 * 8);
            bf16x8 vb0 = *(const bf16x8*)(BT + (size_t)(cb + r0) * K + ks * 32 + q0 * 8);
            bf16x8 vb1 = *(const bf16x8*)(BT + (size_t)(cb + r1) * K + ks * 32 + q1 * 8);
            *(bf16x8*)&lA[q0 * 1024 + r0 * 8] = va0;
            *(bf16x8*)&lA[q1 * 1024 + r1 * 8] = va1;
            *(bf16x8*)&lB[q0 * 1024 + r0 * 8] = vb0;
            *(bf16x8*)&lB[q1 * 1024 + r1 * 8] = vb1;
        }
        __syncthreads();
        bf16x8 af[4], bfr[4];
#pragma unroll
        for (int mi = 0; mi < 4; ++mi)
            af[mi] = *(const bf16x8*)&lA[q * 1024 + (wr * 64 + mi * 16 + l16) * 8];
#pragma unroll
        for (int ni = 0; ni < 4; ++ni)
            bfr[ni] = *(const bf16x8*)&lB[q * 1024 + (wc * 64 + ni * 16 + l16) * 8];
#pragma unroll
        for (int mi = 0; mi < 4; ++mi)
#pragma unroll
            for (int ni = 0; ni < 4; ++ni)
                acc[mi][ni] = __builtin_amdgcn_mfma_f32_16x16x32_bf16(af[mi], bfr[ni], acc[mi][ni], 0, 0, 0);
    }

    if constexpr (EPI == 0) {
#pragma unroll
        for (int ni = 0; ni < 4; ++ni) {
            int col = cb + wc * 64 + ni * 16 + l16;
            float bs = bias[col];
#pragma unroll
            for (int mi = 0; mi < 4; ++mi) {
                int row = rb + wr * 64 + mi * 16 + q * 4;
#pragma unroll
                for (int r = 0; r < 4; ++r) {
                    float v = acc[mi][ni][r] + bs;
                    v = v > 0.f ? v : 0.f;
                    out_b[(size_t)(row + r) * NCtot + col] = f2b(v);
                }
            }
        }
    } else {
#pragma unroll
        for (int ni = 0; ni < 4; ++ni) {
            int col = cb + wc * 64 + ni * 16 + l16;
            float bs = bias[col];
            float s = 0.f, sq = 0.f;
#pragma unroll
            for (int mi = 0; mi < 4; ++mi) {
                int row = rb + wr * 64 + mi * 16 + q * 4;
#pragma unroll
                for (int r = 0; r < 4; ++r) {
                    float v = acc[mi][ni][r] + bs;
                    out_f[(size_t)(row + r) * NCtot + col] = v;
                    if (row + r < NNODES) { s += v; sq += v * v; }
                }
            }
            s  += __shfl_xor(s, 16);  s  += __shfl_xor(s, 32);
            sq += __shfl_xor(sq, 16); sq += __shfl_xor(sq, 32);
            if (lane < 16) {
                atomicAdd(&stat_sum[col], s);
                atomicAdd(&stat_sq[col], sq);
            }
        }
    }
}

__global__ void bn_finalize_kernel(const float* __restrict__ sum, const float* __restrict__ sq,
                                   const float* __restrict__ g, const float* __restrict__ b,
                                   float* __restrict__ scale, float* __restrict__ shift) {
    int d = threadIdx.x;
    float mu = sum[d] * (1.f / NNODES);
    float var = sq[d] * (1.f / NNODES) - mu * mu;
    var = var < 0.f ? 0.f : var;
    float sc = g[d] * rsqrtf(var + 1e-5f);
    scale[d] = sc;
    shift[d] = b[d] - mu * sc;
}

__global__ void bn_apply_kernel(const float* __restrict__ m, const float* __restrict__ scale,
                                const float* __restrict__ shift, float* __restrict__ h, int resid) {
    int t = blockIdx.x * 256 + threadIdx.x;   // NNODES*32 float4 units
    if (t >= NNODES * 32) return;
    int j = t & 31;
    float4 mm = ((const float4*)m)[t];
    float4 sc = ((const float4*)scale)[j];
    float4 sh = ((const float4*)shift)[j];
    float4 v;
    v.x = fmaxf(mm.x * sc.x + sh.x, 0.f);
    v.y = fmaxf(mm.y * sc.y + sh.y, 0.f);
    v.z = fmaxf(mm.z * sc.z + sh.z, 0.f);
    v.w = fmaxf(mm.w * sc.w + sh.w, 0.f);
    if (resid) {
        float4 hp = ((const float4*)h)[t];
        v.x += hp.x; v.y += hp.y; v.z += hp.z; v.w += hp.w;
    }
    ((float4*)h)[t] = v;
}

__device__ __forceinline__ int lbound(const int* __restrict__ b, int key) {
    int lo = 0, hi = NNODES;
    while (lo < hi) { int m = (lo + hi) >> 1; if (b[m] < key) lo = m + 1; else hi = m; }
    return lo;
}

__global__ void pool_kernel(const float* __restrict__ h, const int* __restrict__ batch,
                            float* __restrict__ out) {
    int g = blockIdx.x;
    int d = threadIdx.x & 127, hh = threadIdx.x >> 7;
    int s = lbound(batch, g), e = lbound(batch, g + 1);
    float acc = 0.f;
    for (int r = s + hh; r < e; r += 2) acc += h[(size_t)r * 128 + d];
    __shared__ float buf[128];
    if (hh) buf[d] = acc;
    __syncthreads();
    if (!hh) {
        float tot = acc + buf[d];
        int c = e - s;
        out[g * 128 + d] = tot / (float)(c > 0 ? c : 1);
    }
}

__global__ void vn_update_kernel(const float* __restrict__ tmp, const float* __restrict__ W1,
                                 const float* __restrict__ b1, const float* __restrict__ W2,
                                 const float* __restrict__ b2, float* __restrict__ vn) {
    __shared__ float t[128], t1[128];
    int g = blockIdx.x, d = threadIdx.x;
    t[d] = tmp[g * 128 + d];
    __syncthreads();
    float a = b1[d];
    for (int k = 0; k < 128; ++k) a += t[k] * W1[k * 128 + d];
    t1[d] = fmaxf(a, 0.f);
    __syncthreads();
    float o = b2[d];
    for (int k = 0; k < 128; ++k) o += t1[k] * W2[k * 128 + d];
    vn[g * 128 + d] += o;
}

__global__ void add_vn_kernel(const float* __restrict__ h, const float* __restrict__ vn,
                              const int* __restrict__ batch, float* __restrict__ outp) {
    int t = blockIdx.x * 256 + threadIdx.x;   // NNODES*32
    if (t >= NNODES * 32) return;
    int row = t >> 5, j = t & 31;
    int g = batch[row];
    float4 a = ((const float4*)h)[t];
    float4 b = ((const float4*)vn)[(size_t)g * 32 + j];
    a.x += b.x; a.y += b.y; a.z += b.z; a.w += b.w;
    ((float4*)outp)[t] = a;
}

__global__ void graph_mlp_kernel(const float* __restrict__ gf, const float* __restrict__ W1,
                                 const float* __restrict__ b1, const float* __restrict__ lng,
                                 const float* __restrict__ lnb, const float* __restrict__ W2,
                                 const float* __restrict__ b2, float* __restrict__ out) {
    __shared__ float t[128], t1[128], red[2];
    int g = blockIdx.x, d = threadIdx.x;
    int lane = d & 63, w = d >> 6;
    t[d] = gf[g * 128 + d];
    __syncthreads();
    float a = b1[d];
    for (int k = 0; k < 128; ++k) a += t[k] * W1[k * 128 + d];
    float s = a;
#pragma unroll
    for (int o = 1; o < 64; o <<= 1) s += __shfl_xor(s, o);
    if (lane == 0) red[w] = s;
    __syncthreads();
    float mu = (red[0] + red[1]) * (1.f / 128.f);
    float dv = a - mu;
    float qq = dv * dv;
#pragma unroll
    for (int o = 1; o < 64; o <<= 1) qq += __shfl_xor(qq, o);
    __syncthreads();
    if (lane == 0) red[w] = qq;
    __syncthreads();
    float var = (red[0] + red[1]) * (1.f / 128.f);
    float v = dv * rsqrtf(var + 1e-5f) * lng[d] + lnb[d];
    v = fmaxf(v, 0.f);
    t1[d] = v;
    __syncthreads();
    float o2 = b2[d];
    for (int k = 0; k < 128; ++k) o2 += t1[k] * W2[k * 128 + d];
    out[g * 128 + d] = o2;
}

extern "C" void kernel_launch(void* const* d_in, const int* in_sizes, int n_in,
                              void* d_out, int out_size, void* d_ws, size_t ws_size,
                              hipStream_t stream) {
    const float* x    = (const float*)d_in[0];
    const int*   edge = (const int*)d_in[1];
    const int*   src  = edge;
    const int*   dst  = edge + NEDGES;
    const int*   batch = (const int*)d_in[2];
    const float* nW   = (const float*)d_in[3];
    const float* nb   = (const float*)d_in[4];
    const float* W1s  = (const float*)d_in[5];
    const float* b1s  = (const float*)d_in[6];
    const float* W2s  = (const float*)d_in[7];
    const float* b2s  = (const float*)d_in[8];
    const float* bng  = (const float*)d_in[9];
    const float* bnb  = (const float*)d_in[10];
    const float* vne  = (const float*)d_in[11];
    const float* vW1  = (const float*)d_in[12];
    const float* vb1  = (const float*)d_in[13];
    const float* vW2  = (const float*)d_in[14];
    const float* vb2  = (const float*)d_in[15];
    const float* gW1  = (const float*)d_in[16];
    const float* gb1  = (const float*)d_in[17];
    const float* lng  = (const float*)d_in[18];
    const float* lnb  = (const float*)d_in[19];
    const float* gW2  = (const float*)d_in[20];
    const float* gb2  = (const float*)d_in[21];

    char* ws = (char*)d_ws;
    auto alloc = [&](size_t bytes) { char* p = ws; ws += (bytes + 255) & ~(size_t)255; return p; };
    float*  hf    = (float*)alloc((size_t)NPAD * 128 * 4);
    float*  agg   = (float*)alloc((size_t)NPAD * 128 * 4);
    float*  mbuf  = (float*)alloc((size_t)NPAD * 128 * 4);
    ushort* xb    = (ushort*)alloc((size_t)NPAD * 128 * 2);
    ushort* mid   = (ushort*)alloc((size_t)NPAD * 256 * 2);
    float*  vn    = (float*)alloc((size_t)NGRAPH * 128 * 4);
    float*  tmp   = (float*)alloc((size_t)NGRAPH * 128 * 4);
    ushort* w1t   = (ushort*)alloc((size_t)NLAYER * 256 * 128 * 2);
    ushort* w2t   = (ushort*)alloc((size_t)NLAYER * 128 * 256 * 2);
    float*  stats = (float*)alloc(256 * 4);
    float*  scale = (float*)alloc(128 * 4);
    float*  shift = (float*)alloc(128 * 4);
    float*  colsum = stats;
    float*  colsq  = stats + 128;

    float* outN = (float*)d_out;
    float* outG = outN + (size_t)NNODES * 128;

    prep_w_kernel<<<(2 * NLAYER * 128 * 256 + 255) / 256, 256, 0, stream>>>(W1s, W2s, w1t, w2t);
    node_embed_kernel<<<(NNODES * 128 + 255) / 256, 256, 0, stream>>>(x, nW, nb, hf);
    vn_init_kernel<<<(NGRAPH * 128 + 255) / 256, 256, 0, stream>>>(vne, vn);

    for (int i = 0; i < NLAYER; ++i) {
        hipMemsetAsync(agg, 0, (size_t)NPAD * 128 * 4, stream);
        scatter_add_kernel<<<(NEDGES * 32 + 255) / 256, 256, 0, stream>>>(src, dst, hf, agg);
        add_convert_kernel<<<(NPAD * 32 + 255) / 256, 256, 0, stream>>>(hf, agg, xb);
        gemm_kernel<128, 0><<<dim3(NPAD / 128, 2), 256, 0, stream>>>(
            xb, w1t + (size_t)i * 256 * 128, b1s + i * 256, mid, nullptr, nullptr, nullptr, 256);
        hipMemsetAsync(stats, 0, 256 * 4, stream);
        gemm_kernel<256, 1><<<dim3(NPAD / 128, 1), 256, 0, stream>>>(
            mid, w2t + (size_t)i * 128 * 256, b2s + i * 128, nullptr, mbuf, colsum, colsq, 128);
        bn_finalize_kernel<<<1, 128, 0, stream>>>(colsum, colsq, bng + i * 128, bnb + i * 128, scale, shift);
        bn_apply_kernel<<<(NNODES * 32 + 255) / 256, 256, 0, stream>>>(mbuf, scale, shift, hf, i > 0 ? 1 : 0);
        pool_kernel<<<NGRAPH, 256, 0, stream>>>(hf, batch, tmp);
        vn_update_kernel<<<NGRAPH, 128, 0, stream>>>(tmp, vW1, vb1, vW2, vb2, vn);
        add_vn_kernel<<<(NNODES * 32 + 255) / 256, 256, 0, stream>>>(
            hf, vn, batch, (i == NLAYER - 1) ? outN : hf);
    }
    pool_kernel<<<NGRAPH, 256, 0, stream>>>(outN, batch, tmp);
    graph_mlp_kernel<<<NGRAPH, 128, 0, stream>>>(tmp, gW1, gb1, lng, lnb, gW2, gb2, outG);
}

// Round 2
// 1463.001 us; speedup vs baseline: 4.1311x; 4.1311x over previous
//
#include <hip/hip_runtime.h>
#include <stdint.h>

#define NNODES 100000
#define NEDGES 600000
#define NGRAPH 2048
#define DD 128
#define NLAYER 5
#define NPAD 100096   // 782*128

typedef __attribute__((ext_vector_type(8))) __bf16 bf16x8;
typedef __attribute__((ext_vector_type(4))) float f32x4;

__device__ __forceinline__ ushort f2b(float f) {
    union { float f; uint32_t u; } v; v.f = f;
    uint32_t r = v.u + 0x7FFFu + ((v.u >> 16) & 1u);
    return (ushort)(r >> 16);
}

__global__ void prep_w_kernel(const float* __restrict__ W1s, const float* __restrict__ W2s,
                              ushort* __restrict__ w1t, ushort* __restrict__ w2t) {
    int idx = blockIdx.x * 256 + threadIdx.x;
    const int per = 128 * 256;
    if (idx < NLAYER * per) {
        int i = idx / per, rem = idx % per;
        int n = rem >> 7, k = rem & 127;          // w1t[i][n(256)][k(128)] = W1s[i][k][n]
        w1t[idx] = f2b(W1s[(size_t)i * per + k * 256 + n]);
    } else if (idx < 2 * NLAYER * per) {
        int j = idx - NLAYER * per;
        int i = j / per, rem = j % per;
        int n = rem >> 8, k = rem & 255;          // w2t[i][n(128)][k(256)] = W2s[i][k][n]
        w2t[j] = f2b(W2s[(size_t)i * per + k * 128 + n]);
    }
}

__global__ void node_embed_kernel(const float* __restrict__ x, const float* __restrict__ W,
                                  const float* __restrict__ b, float* __restrict__ h) {
    int idx = blockIdx.x * 256 + threadIdx.x;
    if (idx >= NNODES * 128) return;
    int n = idx >> 7, d = idx & 127;
    float v = b[d];
#pragma unroll
    for (int k = 0; k < 9; ++k) v += x[n * 9 + k] * W[k * 128 + d];
    h[(size_t)n * 128 + d] = v;
}

__global__ void vn_init_kernel(const float* __restrict__ vne, float* __restrict__ vn) {
    int idx = blockIdx.x * 256 + threadIdx.x;
    if (idx >= NGRAPH * 128) return;
    vn[idx] = vne[idx & 127];
}

// ---------- CSR build (once per call; edges constant across layers) ----------

__global__ void deg_kernel(const int* __restrict__ dst, int* __restrict__ deg) {
    int e = blockIdx.x * 256 + threadIdx.x;
    if (e < NEDGES) atomicAdd(&deg[dst[e]], 1);
}

__global__ __launch_bounds__(1024)
void scan_kernel(const int* __restrict__ deg, int* __restrict__ rs, int* __restrict__ cursor) {
    __shared__ int part[1024];
    const int CH = (NNODES + 1023) / 1024;   // 98
    int t = threadIdx.x;
    int base = t * CH;
    int s = 0;
    for (int k = 0; k < CH; ++k) {
        int idx = base + k;
        if (idx < NNODES) s += deg[idx];
    }
    part[t] = s;
    __syncthreads();
    // inclusive Hillis-Steele scan over 1024 partials
    for (int o = 1; o < 1024; o <<= 1) {
        int v = (t >= o) ? part[t - o] : 0;
        __syncthreads();
        part[t] += v;
        __syncthreads();
    }
    int off = part[t] - s;   // exclusive prefix for this thread's chunk
    for (int k = 0; k < CH; ++k) {
        int idx = base + k;
        if (idx < NNODES) {
            rs[idx] = off;
            cursor[idx] = off;
            off += deg[idx];
        }
    }
    if (t == 0) rs[NNODES] = NEDGES;
}

__global__ void csr_scatter_kernel(const int* __restrict__ src, const int* __restrict__ dst,
                                   int* __restrict__ cursor, int* __restrict__ csrc) {
    int e = blockIdx.x * 256 + threadIdx.x;
    if (e < NEDGES) {
        int p = atomicAdd(&cursor[dst[e]], 1);
        csrc[p] = src[e];
    }
}

// ---------- fused GIN aggregation: xb[i] = bf16(h[i] + sum_{j->i} h[j]) ----------

__global__ __launch_bounds__(256)
void gin_agg_kernel(const float* __restrict__ h, const int* __restrict__ rs,
                    const int* __restrict__ csrc, ushort* __restrict__ xb) {
    int slot = threadIdx.x >> 5;           // 8 nodes per block
    int j = threadIdx.x & 31;              // float4 lane within row
    int node = blockIdx.x * 8 + slot;
    if (node >= NNODES) return;
    int s = rs[node], e = rs[node + 1];
    float4 acc = ((const float4*)h)[(size_t)node * 32 + j];
    for (int k = s; k < e; ++k) {
        int sn = csrc[k];
        float4 v = ((const float4*)h)[(size_t)sn * 32 + j];
        acc.x += v.x; acc.y += v.y; acc.z += v.z; acc.w += v.w;
    }
    ushort4 u;
    u.x = f2b(acc.x); u.y = f2b(acc.y); u.z = f2b(acc.z); u.w = f2b(acc.w);
    ((ushort4*)xb)[(size_t)node * 32 + j] = u;
}

// C = A[NPAD,K](bf16) @ BT^T  (BT is [NC,K] bf16, i.e. B transposed), +bias
// EPI 0: relu -> bf16 store to out_b [NPAD][NCtot]
// EPI 1: f32 store to out_f [NPAD][NCtot] + fused BN column sums (rows < NNODES)
template<int K, int EPI>
__global__ __launch_bounds__(256)
void gemm_kernel(const ushort* __restrict__ A, const ushort* __restrict__ BT,
                 const float* __restrict__ bias,
                 ushort* __restrict__ out_b, float* __restrict__ out_f,
                 float* __restrict__ stat_sum, float* __restrict__ stat_sq, int NCtot) {
    __shared__ __align__(16) ushort lA[4096];   // [q][row][8]
    __shared__ __align__(16) ushort lB[4096];   // [q][col][8]
    const int tid = threadIdx.x;
    const int lane = tid & 63, wid = tid >> 6;
    const int wr = wid >> 1, wc = wid & 1;
    const int rb = blockIdx.x * 128, cb = blockIdx.y * 128;
    const int q = lane >> 4, l16 = lane & 15;

    f32x4 acc[4][4] = {};

#pragma unroll
    for (int ks = 0; ks < K / 32; ++ks) {
        __syncthreads();
        {
            int c0 = tid, c1 = tid + 256;
            int r0 = c0 & 127, q0 = c0 >> 7;
            int r1 = c1 & 127, q1 = c1 >> 7;
            bf16x8 va0 = *(const bf16x8*)(A + (size_t)(rb + r0) * K + ks * 32 + q0 * 8);
            bf16x8 va1 = *(const bf16x8*)(A + (size_t)(rb + r1) * K + ks * 32 + q1 * 8);
            bf16x8 vb0 = *(const bf16x8*)(BT + (size_t)(cb + r0) * K + ks * 32 + q0 * 8);
            bf16x8 vb1 = *(const bf16x8*)(BT + (size_t)(cb + r1) * K + ks * 32 + q1 * 8);
            *(bf16x8*)&lA[q0 * 1024 + r0 * 8] = va0;
            *(bf16x8*)&lA[q1 * 1024 + r1 * 8] = va1;
            *(bf16x8*)&lB[q0 * 1024 + r0 * 8] = vb0;
            *(bf16x8*)&lB[q1 * 1024 + r1 * 8] = vb1;
        }
        __syncthreads();
        bf16x8 af[4], bfr[4];
#pragma unroll
        for (int mi = 0; mi < 4; ++mi)
            af[mi] = *(const bf16x8*)&lA[q * 1024 + (wr * 64 + mi * 16 + l16) * 8];
#pragma unroll
        for (int ni = 0; ni < 4; ++ni)
            bfr[ni] = *(const bf16x8*)&lB[q * 1024 + (wc * 64 + ni * 16 + l16) * 8];
#pragma unroll
        for (int mi = 0; mi < 4; ++mi)
#pragma unroll
            for (int ni = 0; ni < 4; ++ni)
                acc[mi][ni] = __builtin_amdgcn_mfma_f32_16x16x32_bf16(af[mi], bfr[ni], acc[mi][ni], 0, 0, 0);
    }

    if constexpr (EPI == 0) {
#pragma unroll
        for (int ni = 0; ni < 4; ++ni) {
            int col = cb + wc * 64 + ni * 16 + l16;
            float bs = bias[col];
#pragma unroll
            for (int mi = 0; mi < 4; ++mi) {
                int row = rb + wr * 64 + mi * 16 + q * 4;
#pragma unroll
                for (int r = 0; r < 4; ++r) {
                    float v = acc[mi][ni][r] + bs;
                    v = v > 0.f ? v : 0.f;
                    out_b[(size_t)(row + r) * NCtot + col] = f2b(v);
                }
            }
        }
    } else {
#pragma unroll
        for (int ni = 0; ni < 4; ++ni) {
            int col = cb + wc * 64 + ni * 16 + l16;
            float bs = bias[col];
            float s = 0.f, sq = 0.f;
#pragma unroll
            for (int mi = 0; mi < 4; ++mi) {
                int row = rb + wr * 64 + mi * 16 + q * 4;
#pragma unroll
                for (int r = 0; r < 4; ++r) {
                    float v = acc[mi][ni][r] + bs;
                    out_f[(size_t)(row + r) * NCtot + col] = v;
                    if (row + r < NNODES) { s += v; sq += v * v; }
                }
            }
            s  += __shfl_xor(s, 16);  s  += __shfl_xor(s, 32);
            sq += __shfl_xor(sq, 16); sq += __shfl_xor(sq, 32);
            if (lane < 16) {
                atomicAdd(&stat_sum[col], s);
                atomicAdd(&stat_sq[col], sq);
            }
        }
    }
}

__global__ void bn_finalize_kernel(const float* __restrict__ sum, const float* __restrict__ sq,
                                   const float* __restrict__ g, const float* __restrict__ b,
                                   float* __restrict__ scale, float* __restrict__ shift) {
    int d = threadIdx.x;
    float mu = sum[d] * (1.f / NNODES);
    float var = sq[d] * (1.f / NNODES) - mu * mu;
    var = var < 0.f ? 0.f : var;
    float sc = g[d] * rsqrtf(var + 1e-5f);
    scale[d] = sc;
    shift[d] = b[d] - mu * sc;
}

__global__ void bn_apply_kernel(const float* __restrict__ m, const float* __restrict__ scale,
                                const float* __restrict__ shift, float* __restrict__ h, int resid) {
    int t = blockIdx.x * 256 + threadIdx.x;   // NNODES*32 float4 units
    if (t >= NNODES * 32) return;
    int j = t & 31;
    float4 mm = ((const float4*)m)[t];
    float4 sc = ((const float4*)scale)[j];
    float4 sh = ((const float4*)shift)[j];
    float4 v;
    v.x = fmaxf(mm.x * sc.x + sh.x, 0.f);
    v.y = fmaxf(mm.y * sc.y + sh.y, 0.f);
    v.z = fmaxf(mm.z * sc.z + sh.z, 0.f);
    v.w = fmaxf(mm.w * sc.w + sh.w, 0.f);
    if (resid) {
        float4 hp = ((const float4*)h)[t];
        v.x += hp.x; v.y += hp.y; v.z += hp.z; v.w += hp.w;
    }
    ((float4*)h)[t] = v;
}

__device__ __forceinline__ int lbound(const int* __restrict__ b, int key) {
    int lo = 0, hi = NNODES;
    while (lo < hi) { int m = (lo + hi) >> 1; if (b[m] < key) lo = m + 1; else hi = m; }
    return lo;
}

__global__ void pool_kernel(const float* __restrict__ h, const int* __restrict__ batch,
                            float* __restrict__ out) {
    int g = blockIdx.x;
    int d = threadIdx.x & 127, hh = threadIdx.x >> 7;
    int s = lbound(batch, g), e = lbound(batch, g + 1);
    float acc = 0.f;
    for (int r = s + hh; r < e; r += 2) acc += h[(size_t)r * 128 + d];
    __shared__ float buf[128];
    if (hh) buf[d] = acc;
    __syncthreads();
    if (!hh) {
        float tot = acc + buf[d];
        int c = e - s;
        out[g * 128 + d] = tot / (float)(c > 0 ? c : 1);
    }
}

__global__ void vn_update_kernel(const float* __restrict__ tmp, const float* __restrict__ W1,
                                 const float* __restrict__ b1, const float* __restrict__ W2,
                                 const float* __restrict__ b2, float* __restrict__ vn) {
    __shared__ float t[128], t1[128];
    int g = blockIdx.x, d = threadIdx.x;
    t[d] = tmp[g * 128 + d];
    __syncthreads();
    float a = b1[d];
    for (int k = 0; k < 128; ++k) a += t[k] * W1[k * 128 + d];
    t1[d] = fmaxf(a, 0.f);
    __syncthreads();
    float o = b2[d];
    for (int k = 0; k < 128; ++k) o += t1[k] * W2[k * 128 + d];
    vn[g * 128 + d] += o;
}

__global__ void add_vn_kernel(const float* __restrict__ h, const float* __restrict__ vn,
                              const int* __restrict__ batch, float* __restrict__ outp) {
    int t = blockIdx.x * 256 + threadIdx.x;   // NNODES*32
    if (t >= NNODES * 32) return;
    int row = t >> 5, j = t & 31;
    int g = batch[row];
    float4 a = ((const float4*)h)[t];
    float4 b = ((const float4*)vn)[(size_t)g * 32 + j];
    a.x += b.x; a.y += b.y; a.z += b.z; a.w += b.w;
    ((float4*)outp)[t] = a;
}

__global__ void graph_mlp_kernel(const float* __restrict__ gf, const float* __restrict__ W1,
                                 const float* __restrict__ b1, const float* __restrict__ lng,
                                 const float* __restrict__ lnb, const float* __restrict__ W2,
                                 const float* __restrict__ b2, float* __restrict__ out) {
    __shared__ float t[128], t1[128], red[2];
    int g = blockIdx.x, d = threadIdx.x;
    int lane = d & 63, w = d >> 6;
    t[d] = gf[g * 128 + d];
    __syncthreads();
    float a = b1[d];
    for (int k = 0; k < 128; ++k) a += t[k] * W1[k * 128 + d];
    float s = a;
#pragma unroll
    for (int o = 1; o < 64; o <<= 1) s += __shfl_xor(s, o);
    if (lane == 0) red[w] = s;
    __syncthreads();
    float mu = (red[0] + red[1]) * (1.f / 128.f);
    float dv = a - mu;
    float qq = dv * dv;
#pragma unroll
    for (int o = 1; o < 64; o <<= 1) qq += __shfl_xor(qq, o);
    __syncthreads();
    if (lane == 0) red[w] = qq;
    __syncthreads();
    float var = (red[0] + red[1]) * (1.f / 128.f);
    float v = dv * rsqrtf(var + 1e-5f) * lng[d] + lnb[d];
    v = fmaxf(v, 0.f);
    t1[d] = v;
    __syncthreads();
    float o2 = b2[d];
    for (int k = 0; k < 128; ++k) o2 += t1[k] * W2[k * 128 + d];
    out[g * 128 + d] = o2;
}

extern "C" void kernel_launch(void* const* d_in, const int* in_sizes, int n_in,
                              void* d_out, int out_size, void* d_ws, size_t ws_size,
                              hipStream_t stream) {
    const float* x    = (const float*)d_in[0];
    const int*   edge = (const int*)d_in[1];
    const int*   src  = edge;
    const int*   dst  = edge + NEDGES;
    const int*   batch = (const int*)d_in[2];
    const float* nW   = (const float*)d_in[3];
    const float* nb   = (const float*)d_in[4];
    const float* W1s  = (const float*)d_in[5];
    const float* b1s  = (const float*)d_in[6];
    const float* W2s  = (const float*)d_in[7];
    const float* b2s  = (const float*)d_in[8];
    const float* bng  = (const float*)d_in[9];
    const float* bnb  = (const float*)d_in[10];
    const float* vne  = (const float*)d_in[11];
    const float* vW1  = (const float*)d_in[12];
    const float* vb1  = (const float*)d_in[13];
    const float* vW2  = (const float*)d_in[14];
    const float* vb2  = (const float*)d_in[15];
    const float* gW1  = (const float*)d_in[16];
    const float* gb1  = (const float*)d_in[17];
    const float* lng  = (const float*)d_in[18];
    const float* lnb  = (const float*)d_in[19];
    const float* gW2  = (const float*)d_in[20];
    const float* gb2  = (const float*)d_in[21];

    char* ws = (char*)d_ws;
    auto alloc = [&](size_t bytes) { char* p = ws; ws += (bytes + 255) & ~(size_t)255; return p; };
    float*  hf    = (float*)alloc((size_t)NPAD * 128 * 4);
    float*  mbuf  = (float*)alloc((size_t)NPAD * 128 * 4);
    ushort* xb    = (ushort*)alloc((size_t)NPAD * 128 * 2);
    ushort* mid   = (ushort*)alloc((size_t)NPAD * 256 * 2);
    float*  vn    = (float*)alloc((size_t)NGRAPH * 128 * 4);
    float*  tmp   = (float*)alloc((size_t)NGRAPH * 128 * 4);
    ushort* w1t   = (ushort*)alloc((size_t)NLAYER * 256 * 128 * 2);
    ushort* w2t   = (ushort*)alloc((size_t)NLAYER * 128 * 256 * 2);
    float*  stats = (float*)alloc(256 * 4);
    float*  scale = (float*)alloc(128 * 4);
    float*  shift = (float*)alloc(128 * 4);
    int*    deg   = (int*)alloc((size_t)NNODES * 4);
    int*    rs    = (int*)alloc((size_t)(NNODES + 1) * 4);
    int*    cursor= (int*)alloc((size_t)NNODES * 4);
    int*    csrc  = (int*)alloc((size_t)NEDGES * 4);
    float*  colsum = stats;
    float*  colsq  = stats + 128;

    float* outN = (float*)d_out;
    float* outG = outN + (size_t)NNODES * 128;

    // CSR build (edges constant across layers)
    hipMemsetAsync(deg, 0, (size_t)NNODES * 4, stream);
    deg_kernel<<<(NEDGES + 255) / 256, 256, 0, stream>>>(dst, deg);
    scan_kernel<<<1, 1024, 0, stream>>>(deg, rs, cursor);
    csr_scatter_kernel<<<(NEDGES + 255) / 256, 256, 0, stream>>>(src, dst, cursor, csrc);

    prep_w_kernel<<<(2 * NLAYER * 128 * 256 + 255) / 256, 256, 0, stream>>>(W1s, W2s, w1t, w2t);
    node_embed_kernel<<<(NNODES * 128 + 255) / 256, 256, 0, stream>>>(x, nW, nb, hf);
    vn_init_kernel<<<(NGRAPH * 128 + 255) / 256, 256, 0, stream>>>(vne, vn);

    for (int i = 0; i < NLAYER; ++i) {
        gin_agg_kernel<<<(NNODES + 7) / 8, 256, 0, stream>>>(hf, rs, csrc, xb);
        gemm_kernel<128, 0><<<dim3(NPAD / 128, 2), 256, 0, stream>>>(
            xb, w1t + (size_t)i * 256 * 128, b1s + i * 256, mid, nullptr, nullptr, nullptr, 256);
        hipMemsetAsync(stats, 0, 256 * 4, stream);
        gemm_kernel<256, 1><<<dim3(NPAD / 128, 1), 256, 0, stream>>>(
            mid, w2t + (size_t)i * 128 * 256, b2s + i * 128, nullptr, mbuf, colsum, colsq, 128);
        bn_finalize_kernel<<<1, 128, 0, stream>>>(colsum, colsq, bng + i * 128, bnb + i * 128, scale, shift);
        bn_apply_kernel<<<(NNODES * 32 + 255) / 256, 256, 0, stream>>>(mbuf, scale, shift, hf, i > 0 ? 1 : 0);
        pool_kernel<<<NGRAPH, 256, 0, stream>>>(hf, batch, tmp);
        vn_update_kernel<<<NGRAPH, 128, 0, stream>>>(tmp, vW1, vb1, vW2, vb2, vn);
        add_vn_kernel<<<(NNODES * 32 + 255) / 256, 256, 0, stream>>>(
            hf, vn, batch, (i == NLAYER - 1) ? outN : hf);
    }
    pool_kernel<<<NGRAPH, 256, 0, stream>>>(outN, batch, tmp);
    graph_mlp_kernel<<<NGRAPH, 128, 0, stream>>>(tmp, gW1, gb1, lng, lnb, gW2, gb2, outG);
}

// Round 3
// 1206.377 us; speedup vs baseline: 5.0099x; 1.2127x over previous
//
#include <hip/hip_runtime.h>
#include <stdint.h>

#define NNODES 100000
#define NEDGES 600000
#define NGRAPH 2048
#define DD 128
#define NLAYER 5
#define NPAD 100096   // 782*128
#define SCAN_NB 391   // ceil(NNODES/256)

typedef __attribute__((ext_vector_type(8))) __bf16 bf16x8;
typedef __attribute__((ext_vector_type(4))) float f32x4;

__device__ __forceinline__ ushort f2b(float f) {
    union { float f; uint32_t u; } v; v.f = f;
    uint32_t r = v.u + 0x7FFFu + ((v.u >> 16) & 1u);
    return (ushort)(r >> 16);
}

__global__ void prep_w_kernel(const float* __restrict__ W1s, const float* __restrict__ W2s,
                              ushort* __restrict__ w1t, ushort* __restrict__ w2t) {
    int idx = blockIdx.x * 256 + threadIdx.x;
    const int per = 128 * 256;
    if (idx < NLAYER * per) {
        int i = idx / per, rem = idx % per;
        int n = rem >> 7, k = rem & 127;          // w1t[i][n(256)][k(128)] = W1s[i][k][n]
        w1t[idx] = f2b(W1s[(size_t)i * per + k * 256 + n]);
    } else if (idx < 2 * NLAYER * per) {
        int j = idx - NLAYER * per;
        int i = j / per, rem = j % per;
        int n = rem >> 8, k = rem & 255;          // w2t[i][n(128)][k(256)] = W2s[i][k][n]
        w2t[j] = f2b(W2s[(size_t)i * per + k * 128 + n]);
    }
}

__global__ void node_embed_kernel(const float* __restrict__ x, const float* __restrict__ W,
                                  const float* __restrict__ b, float* __restrict__ h) {
    int idx = blockIdx.x * 256 + threadIdx.x;
    if (idx >= NNODES * 128) return;
    int n = idx >> 7, d = idx & 127;
    float v = b[d];
#pragma unroll
    for (int k = 0; k < 9; ++k) v += x[n * 9 + k] * W[k * 128 + d];
    h[(size_t)n * 128 + d] = v;
}

__global__ void vn_init_kernel(const float* __restrict__ vne, float* __restrict__ vn) {
    int idx = blockIdx.x * 256 + threadIdx.x;
    if (idx >= NGRAPH * 128) return;
    vn[idx] = vne[idx & 127];
}

// ---------- CSR build (once per call; edges constant across layers) ----------

__global__ void deg_kernel(const int* __restrict__ dst, int* __restrict__ deg) {
    int e = blockIdx.x * 256 + threadIdx.x;
    if (e < NEDGES) atomicAdd(&deg[dst[e]], 1);
}

// stage 1: per-block sums of deg
__global__ void scan_part_kernel(const int* __restrict__ deg, int* __restrict__ partials) {
    int i = blockIdx.x * 256 + threadIdx.x;
    int lane = threadIdx.x & 63, w = threadIdx.x >> 6;
    int v = (i < NNODES) ? deg[i] : 0;
#pragma unroll
    for (int o = 1; o < 64; o <<= 1) v += __shfl_xor(v, o);
    __shared__ int ws[4];
    if (lane == 0) ws[w] = v;
    __syncthreads();
    if (threadIdx.x == 0) partials[blockIdx.x] = ws[0] + ws[1] + ws[2] + ws[3];
}

// stage 2: exclusive scan over the 391 partials (single block)
__global__ __launch_bounds__(512)
void scan_top_kernel(int* __restrict__ partials) {
    __shared__ int s[512];
    int t = threadIdx.x;
    int v = (t < SCAN_NB) ? partials[t] : 0;
    s[t] = v;
    __syncthreads();
#pragma unroll
    for (int o = 1; o < 512; o <<= 1) {
        int n = (t >= o) ? s[t - o] : 0;
        __syncthreads();
        s[t] += n;
        __syncthreads();
    }
    if (t < SCAN_NB) partials[t] = s[t] - v;   // exclusive
}

// stage 3: in-block exclusive scan + global offset -> rs, cursor
__global__ void scan_blocks_kernel(const int* __restrict__ deg, const int* __restrict__ partials,
                                   int* __restrict__ rs, int* __restrict__ cursor) {
    int i = blockIdx.x * 256 + threadIdx.x;
    int lane = threadIdx.x & 63, w = threadIdx.x >> 6;
    int v = (i < NNODES) ? deg[i] : 0;
    int x = v;
#pragma unroll
    for (int o = 1; o < 64; o <<= 1) {
        int n = __shfl_up(x, o);
        if (lane >= o) x += n;
    }
    __shared__ int ws[4];
    if (lane == 63) ws[w] = x;
    __syncthreads();
    if (threadIdx.x == 0) {
        int a = 0;
#pragma unroll
        for (int k = 0; k < 4; ++k) { int t = ws[k]; ws[k] = a; a += t; }
    }
    __syncthreads();
    int excl = (x - v) + ws[w] + partials[blockIdx.x];
    if (i < NNODES) { rs[i] = excl; cursor[i] = excl; }
    if (i == 0) rs[NNODES] = NEDGES;
}

__global__ void csr_scatter_kernel(const int* __restrict__ src, const int* __restrict__ dst,
                                   int* __restrict__ cursor, int* __restrict__ csrc) {
    int e = blockIdx.x * 256 + threadIdx.x;
    if (e < NEDGES) {
        int p = atomicAdd(&cursor[dst[e]], 1);
        csrc[p] = src[e];
    }
}

// ---------- fused GIN aggregation: xb[i] = bf16(h[i] + sum_{j->i} h[j]) ----------

__global__ __launch_bounds__(256)
void gin_agg_kernel(const float* __restrict__ h, const int* __restrict__ rs,
                    const int* __restrict__ csrc, ushort* __restrict__ xb) {
    int slot = threadIdx.x >> 5;           // 8 nodes per block
    int j = threadIdx.x & 31;              // float4 lane within row
    int node = blockIdx.x * 8 + slot;
    if (node >= NNODES) return;
    int s = rs[node], e = rs[node + 1];
    float4 acc = ((const float4*)h)[(size_t)node * 32 + j];
    for (int k = s; k < e; ++k) {
        int sn = csrc[k];
        float4 v = ((const float4*)h)[(size_t)sn * 32 + j];
        acc.x += v.x; acc.y += v.y; acc.z += v.z; acc.w += v.w;
    }
    ushort4 u;
    u.x = f2b(acc.x); u.y = f2b(acc.y); u.z = f2b(acc.z); u.w = f2b(acc.w);
    ((ushort4*)xb)[(size_t)node * 32 + j] = u;
}

// C = A[NPAD,K](bf16) @ BT^T  (BT is [NC,K] bf16, i.e. B transposed), +bias
// EPI 0: relu -> bf16 store to out_b [NPAD][NCtot]
// EPI 1: f32 store to out_f [NPAD][NCtot] + fused BN column sums (rows < NNODES)
template<int K, int EPI>
__global__ __launch_bounds__(256)
void gemm_kernel(const ushort* __restrict__ A, const ushort* __restrict__ BT,
                 const float* __restrict__ bias,
                 ushort* __restrict__ out_b, float* __restrict__ out_f,
                 float* __restrict__ stat_sum, float* __restrict__ stat_sq, int NCtot) {
    __shared__ __align__(16) ushort lA[4096];   // [q][row][8]
    __shared__ __align__(16) ushort lB[4096];   // [q][col][8]
    const int tid = threadIdx.x;
    const int lane = tid & 63, wid = tid >> 6;
    const int wr = wid >> 1, wc = wid & 1;
    const int rb = blockIdx.x * 128, cb = blockIdx.y * 128;
    const int q = lane >> 4, l16 = lane & 15;

    f32x4 acc[4][4] = {};

#pragma unroll
    for (int ks = 0; ks < K / 32; ++ks) {
        __syncthreads();
        {
            int c0 = tid, c1 = tid + 256;
            int r0 = c0 & 127, q0 = c0 >> 7;
            int r1 = c1 & 127, q1 = c1 >> 7;
            bf16x8 va0 = *(const bf16x8*)(A + (size_t)(rb + r0) * K + ks * 32 + q0 * 8);
            bf16x8 va1 = *(const bf16x8*)(A + (size_t)(rb + r1) * K + ks * 32 + q1 * 8);
            bf16x8 vb0 = *(const bf16x8*)(BT + (size_t)(cb + r0) * K + ks * 32 + q0 * 8);
            bf16x8 vb1 = *(const bf16x8*)(BT + (size_t)(cb + r1) * K + ks * 32 + q1 * 8);
            *(bf16x8*)&lA[q0 * 1024 + r0 * 8] = va0;
            *(bf16x8*)&lA[q1 * 1024 + r1 * 8] = va1;
            *(bf16x8*)&lB[q0 * 1024 + r0 * 8] = vb0;
            *(bf16x8*)&lB[q1 * 1024 + r1 * 8] = vb1;
        }
        __syncthreads();
        bf16x8 af[4], bfr[4];
#pragma unroll
        for (int mi = 0; mi < 4; ++mi)
            af[mi] = *(const bf16x8*)&lA[q * 1024 + (wr * 64 + mi * 16 + l16) * 8];
#pragma unroll
        for (int ni = 0; ni < 4; ++ni)
            bfr[ni] = *(const bf16x8*)&lB[q * 1024 + (wc * 64 + ni * 16 + l16) * 8];
#pragma unroll
        for (int mi = 0; mi < 4; ++mi)
#pragma unroll
            for (int ni = 0; ni < 4; ++ni)
                acc[mi][ni] = __builtin_amdgcn_mfma_f32_16x16x32_bf16(af[mi], bfr[ni], acc[mi][ni], 0, 0, 0);
    }

    if constexpr (EPI == 0) {
#pragma unroll
        for (int ni = 0; ni < 4; ++ni) {
            int col = cb + wc * 64 + ni * 16 + l16;
            float bs = bias[col];
#pragma unroll
            for (int mi = 0; mi < 4; ++mi) {
                int row = rb + wr * 64 + mi * 16 + q * 4;
#pragma unroll
                for (int r = 0; r < 4; ++r) {
                    float v = acc[mi][ni][r] + bs;
                    v = v > 0.f ? v : 0.f;
                    out_b[(size_t)(row + r) * NCtot + col] = f2b(v);
                }
            }
        }
    } else {
#pragma unroll
        for (int ni = 0; ni < 4; ++ni) {
            int col = cb + wc * 64 + ni * 16 + l16;
            float bs = bias[col];
            float s = 0.f, sq = 0.f;
#pragma unroll
            for (int mi = 0; mi < 4; ++mi) {
                int row = rb + wr * 64 + mi * 16 + q * 4;
#pragma unroll
                for (int r = 0; r < 4; ++r) {
                    float v = acc[mi][ni][r] + bs;
                    out_f[(size_t)(row + r) * NCtot + col] = v;
                    if (row + r < NNODES) { s += v; sq += v * v; }
                }
            }
            s  += __shfl_xor(s, 16);  s  += __shfl_xor(s, 32);
            sq += __shfl_xor(sq, 16); sq += __shfl_xor(sq, 32);
            if (lane < 16) {
                atomicAdd(&stat_sum[col], s);
                atomicAdd(&stat_sq[col], sq);
            }
        }
    }
}

__global__ void bn_finalize_kernel(const float* __restrict__ sum, const float* __restrict__ sq,
                                   const float* __restrict__ g, const float* __restrict__ b,
                                   float* __restrict__ scale, float* __restrict__ shift) {
    int d = threadIdx.x;
    float mu = sum[d] * (1.f / NNODES);
    float var = sq[d] * (1.f / NNODES) - mu * mu;
    var = var < 0.f ? 0.f : var;
    float sc = g[d] * rsqrtf(var + 1e-5f);
    scale[d] = sc;
    shift[d] = b[d] - mu * sc;
}

__global__ void bn_apply_kernel(const float* __restrict__ m, const float* __restrict__ scale,
                                const float* __restrict__ shift, float* __restrict__ h, int resid) {
    int t = blockIdx.x * 256 + threadIdx.x;   // NNODES*32 float4 units
    if (t >= NNODES * 32) return;
    int j = t & 31;
    float4 mm = ((const float4*)m)[t];
    float4 sc = ((const float4*)scale)[j];
    float4 sh = ((const float4*)shift)[j];
    float4 v;
    v.x = fmaxf(mm.x * sc.x + sh.x, 0.f);
    v.y = fmaxf(mm.y * sc.y + sh.y, 0.f);
    v.z = fmaxf(mm.z * sc.z + sh.z, 0.f);
    v.w = fmaxf(mm.w * sc.w + sh.w, 0.f);
    if (resid) {
        float4 hp = ((const float4*)h)[t];
        v.x += hp.x; v.y += hp.y; v.z += hp.z; v.w += hp.w;
    }
    ((float4*)h)[t] = v;
}

__device__ __forceinline__ int lbound(const int* __restrict__ b, int key) {
    int lo = 0, hi = NNODES;
    while (lo < hi) { int m = (lo + hi) >> 1; if (b[m] < key) lo = m + 1; else hi = m; }
    return lo;
}

__global__ void pool_kernel(const float* __restrict__ h, const int* __restrict__ batch,
                            float* __restrict__ out) {
    int g = blockIdx.x;
    int d = threadIdx.x & 127, hh = threadIdx.x >> 7;
    int s = lbound(batch, g), e = lbound(batch, g + 1);
    float acc = 0.f;
    for (int r = s + hh; r < e; r += 2) acc += h[(size_t)r * 128 + d];
    __shared__ float buf[128];
    if (hh) buf[d] = acc;
    __syncthreads();
    if (!hh) {
        float tot = acc + buf[d];
        int c = e - s;
        out[g * 128 + d] = tot / (float)(c > 0 ? c : 1);
    }
}

__global__ void vn_update_kernel(const float* __restrict__ tmp, const float* __restrict__ W1,
                                 const float* __restrict__ b1, const float* __restrict__ W2,
                                 const float* __restrict__ b2, float* __restrict__ vn) {
    __shared__ float t[128], t1[128];
    int g = blockIdx.x, d = threadIdx.x;
    t[d] = tmp[g * 128 + d];
    __syncthreads();
    float a = b1[d];
    for (int k = 0; k < 128; ++k) a += t[k] * W1[k * 128 + d];
    t1[d] = fmaxf(a, 0.f);
    __syncthreads();
    float o = b2[d];
    for (int k = 0; k < 128; ++k) o += t1[k] * W2[k * 128 + d];
    vn[g * 128 + d] += o;
}

__global__ void add_vn_kernel(const float* __restrict__ h, const float* __restrict__ vn,
                              const int* __restrict__ batch, float* __restrict__ outp) {
    int t = blockIdx.x * 256 + threadIdx.x;   // NNODES*32
    if (t >= NNODES * 32) return;
    int row = t >> 5, j = t & 31;
    int g = batch[row];
    float4 a = ((const float4*)h)[t];
    float4 b = ((const float4*)vn)[(size_t)g * 32 + j];
    a.x += b.x; a.y += b.y; a.z += b.z; a.w += b.w;
    ((float4*)outp)[t] = a;
}

__global__ void graph_mlp_kernel(const float* __restrict__ gf, const float* __restrict__ W1,
                                 const float* __restrict__ b1, const float* __restrict__ lng,
                                 const float* __restrict__ lnb, const float* __restrict__ W2,
                                 const float* __restrict__ b2, float* __restrict__ out) {
    __shared__ float t[128], t1[128], red[2];
    int g = blockIdx.x, d = threadIdx.x;
    int lane = d & 63, w = d >> 6;
    t[d] = gf[g * 128 + d];
    __syncthreads();
    float a = b1[d];
    for (int k = 0; k < 128; ++k) a += t[k] * W1[k * 128 + d];
    float s = a;
#pragma unroll
    for (int o = 1; o < 64; o <<= 1) s += __shfl_xor(s, o);
    if (lane == 0) red[w] = s;
    __syncthreads();
    float mu = (red[0] + red[1]) * (1.f / 128.f);
    float dv = a - mu;
    float qq = dv * dv;
#pragma unroll
    for (int o = 1; o < 64; o <<= 1) qq += __shfl_xor(qq, o);
    __syncthreads();
    if (lane == 0) red[w] = qq;
    __syncthreads();
    float var = (red[0] + red[1]) * (1.f / 128.f);
    float v = dv * rsqrtf(var + 1e-5f) * lng[d] + lnb[d];
    v = fmaxf(v, 0.f);
    t1[d] = v;
    __syncthreads();
    float o2 = b2[d];
    for (int k = 0; k < 128; ++k) o2 += t1[k] * W2[k * 128 + d];
    out[g * 128 + d] = o2;
}

extern "C" void kernel_launch(void* const* d_in, const int* in_sizes, int n_in,
                              void* d_out, int out_size, void* d_ws, size_t ws_size,
                              hipStream_t stream) {
    const float* x    = (const float*)d_in[0];
    const int*   edge = (const int*)d_in[1];
    const int*   src  = edge;
    const int*   dst  = edge + NEDGES;
    const int*   batch = (const int*)d_in[2];
    const float* nW   = (const float*)d_in[3];
    const float* nb   = (const float*)d_in[4];
    const float* W1s  = (const float*)d_in[5];
    const float* b1s  = (const float*)d_in[6];
    const float* W2s  = (const float*)d_in[7];
    const float* b2s  = (const float*)d_in[8];
    const float* bng  = (const float*)d_in[9];
    const float* bnb  = (const float*)d_in[10];
    const float* vne  = (const float*)d_in[11];
    const float* vW1  = (const float*)d_in[12];
    const float* vb1  = (const float*)d_in[13];
    const float* vW2  = (const float*)d_in[14];
    const float* vb2  = (const float*)d_in[15];
    const float* gW1  = (const float*)d_in[16];
    const float* gb1  = (const float*)d_in[17];
    const float* lng  = (const float*)d_in[18];
    const float* lnb  = (const float*)d_in[19];
    const float* gW2  = (const float*)d_in[20];
    const float* gb2  = (const float*)d_in[21];

    char* ws = (char*)d_ws;
    auto alloc = [&](size_t bytes) { char* p = ws; ws += (bytes + 255) & ~(size_t)255; return p; };
    float*  hf    = (float*)alloc((size_t)NPAD * 128 * 4);
    float*  mbuf  = (float*)alloc((size_t)NPAD * 128 * 4);
    ushort* xb    = (ushort*)alloc((size_t)NPAD * 128 * 2);
    ushort* mid   = (ushort*)alloc((size_t)NPAD * 256 * 2);
    float*  vn    = (float*)alloc((size_t)NGRAPH * 128 * 4);
    float*  tmp   = (float*)alloc((size_t)NGRAPH * 128 * 4);
    ushort* w1t   = (ushort*)alloc((size_t)NLAYER * 256 * 128 * 2);
    ushort* w2t   = (ushort*)alloc((size_t)NLAYER * 128 * 256 * 2);
    float*  stats = (float*)alloc(256 * 4);
    float*  scale = (float*)alloc(128 * 4);
    float*  shift = (float*)alloc(128 * 4);
    int*    deg   = (int*)alloc((size_t)NNODES * 4);
    int*    rs    = (int*)alloc((size_t)(NNODES + 1) * 4);
    int*    cursor= (int*)alloc((size_t)NNODES * 4);
    int*    csrc  = (int*)alloc((size_t)NEDGES * 4);
    int*    partials = (int*)alloc((size_t)SCAN_NB * 4);
    float*  colsum = stats;
    float*  colsq  = stats + 128;

    float* outN = (float*)d_out;
    float* outG = outN + (size_t)NNODES * 128;

    // CSR build (edges constant across layers)
    hipMemsetAsync(deg, 0, (size_t)NNODES * 4, stream);
    deg_kernel<<<(NEDGES + 255) / 256, 256, 0, stream>>>(dst, deg);
    scan_part_kernel<<<SCAN_NB, 256, 0, stream>>>(deg, partials);
    scan_top_kernel<<<1, 512, 0, stream>>>(partials);
    scan_blocks_kernel<<<SCAN_NB, 256, 0, stream>>>(deg, partials, rs, cursor);
    csr_scatter_kernel<<<(NEDGES + 255) / 256, 256, 0, stream>>>(src, dst, cursor, csrc);

    prep_w_kernel<<<(2 * NLAYER * 128 * 256 + 255) / 256, 256, 0, stream>>>(W1s, W2s, w1t, w2t);
    node_embed_kernel<<<(NNODES * 128 + 255) / 256, 256, 0, stream>>>(x, nW, nb, hf);
    vn_init_kernel<<<(NGRAPH * 128 + 255) / 256, 256, 0, stream>>>(vne, vn);

    for (int i = 0; i < NLAYER; ++i) {
        gin_agg_kernel<<<(NNODES + 7) / 8, 256, 0, stream>>>(hf, rs, csrc, xb);
        gemm_kernel<128, 0><<<dim3(NPAD / 128, 2), 256, 0, stream>>>(
            xb, w1t + (size_t)i * 256 * 128, b1s + i * 256, mid, nullptr, nullptr, nullptr, 256);
        hipMemsetAsync(stats, 0, 256 * 4, stream);
        gemm_kernel<256, 1><<<dim3(NPAD / 128, 1), 256, 0, stream>>>(
            mid, w2t + (size_t)i * 128 * 256, b2s + i * 128, nullptr, mbuf, colsum, colsq, 128);
        bn_finalize_kernel<<<1, 128, 0, stream>>>(colsum, colsq, bng + i * 128, bnb + i * 128, scale, shift);
        bn_apply_kernel<<<(NNODES * 32 + 255) / 256, 256, 0, stream>>>(mbuf, scale, shift, hf, i > 0 ? 1 : 0);
        pool_kernel<<<NGRAPH, 256, 0, stream>>>(hf, batch, tmp);
        vn_update_kernel<<<NGRAPH, 128, 0, stream>>>(tmp, vW1, vb1, vW2, vb2, vn);
        add_vn_kernel<<<(NNODES * 32 + 255) / 256, 256, 0, stream>>>(
            hf, vn, batch, (i == NLAYER - 1) ? outN : hf);
    }
    pool_kernel<<<NGRAPH, 256, 0, stream>>>(outN, batch, tmp);
    graph_mlp_kernel<<<NGRAPH, 128, 0, stream>>>(tmp, gW1, gb1, lng, lnb, gW2, gb2, outG);
}

// Round 4
// 1090.811 us; speedup vs baseline: 5.5407x; 1.1059x over previous
//
#include <hip/hip_runtime.h>
#include <stdint.h>

#define NNODES 100000
#define NEDGES 600000
#define NGRAPH 2048
#define DD 128
#define NLAYER 5
#define NPAD 100096   // 782*128
#define SCAN_NB 391   // ceil(NNODES/256)

typedef __attribute__((ext_vector_type(8))) __bf16 bf16x8;
typedef __attribute__((ext_vector_type(4))) float f32x4;

__device__ __forceinline__ ushort f2b(float f) {
    union { float f; uint32_t u; } v; v.f = f;
    uint32_t r = v.u + 0x7FFFu + ((v.u >> 16) & 1u);
    return (ushort)(r >> 16);
}

__global__ void prep_w_kernel(const float* __restrict__ W1s, const float* __restrict__ W2s,
                              ushort* __restrict__ w1t, ushort* __restrict__ w2t) {
    int idx = blockIdx.x * 256 + threadIdx.x;
    const int per = 128 * 256;
    if (idx < NLAYER * per) {
        int i = idx / per, rem = idx % per;
        int n = rem >> 7, k = rem & 127;          // w1t[i][n(256)][k(128)] = W1s[i][k][n]
        w1t[idx] = f2b(W1s[(size_t)i * per + k * 256 + n]);
    } else if (idx < 2 * NLAYER * per) {
        int j = idx - NLAYER * per;
        int i = j / per, rem = j % per;
        int n = rem >> 8, k = rem & 255;          // w2t[i][n(128)][k(256)] = W2s[i][k][n]
        w2t[j] = f2b(W2s[(size_t)i * per + k * 128 + n]);
    }
}

__global__ void node_embed_kernel(const float* __restrict__ x, const float* __restrict__ W,
                                  const float* __restrict__ b, float* __restrict__ h) {
    int idx = blockIdx.x * 256 + threadIdx.x;
    if (idx >= NNODES * 128) return;
    int n = idx >> 7, d = idx & 127;
    float v = b[d];
#pragma unroll
    for (int k = 0; k < 9; ++k) v += x[n * 9 + k] * W[k * 128 + d];
    h[(size_t)n * 128 + d] = v;
}

__global__ void vn_init_kernel(const float* __restrict__ vne, float* __restrict__ vn) {
    int idx = blockIdx.x * 256 + threadIdx.x;
    if (idx >= NGRAPH * 128) return;
    vn[idx] = vne[idx & 127];
}

// ---------- CSR build (once per call; edges constant across layers) ----------

__global__ void deg_kernel(const int* __restrict__ dst, int* __restrict__ deg) {
    int e = blockIdx.x * 256 + threadIdx.x;
    if (e < NEDGES) atomicAdd(&deg[dst[e]], 1);
}

// stage 1: per-block sums of deg
__global__ void scan_part_kernel(const int* __restrict__ deg, int* __restrict__ partials) {
    int i = blockIdx.x * 256 + threadIdx.x;
    int lane = threadIdx.x & 63, w = threadIdx.x >> 6;
    int v = (i < NNODES) ? deg[i] : 0;
#pragma unroll
    for (int o = 1; o < 64; o <<= 1) v += __shfl_xor(v, o);
    __shared__ int ws[4];
    if (lane == 0) ws[w] = v;
    __syncthreads();
    if (threadIdx.x == 0) partials[blockIdx.x] = ws[0] + ws[1] + ws[2] + ws[3];
}

// stage 2: exclusive scan over the 391 partials (single block)
__global__ __launch_bounds__(512)
void scan_top_kernel(int* __restrict__ partials) {
    __shared__ int s[512];
    int t = threadIdx.x;
    int v = (t < SCAN_NB) ? partials[t] : 0;
    s[t] = v;
    __syncthreads();
#pragma unroll
    for (int o = 1; o < 512; o <<= 1) {
        int n = (t >= o) ? s[t - o] : 0;
        __syncthreads();
        s[t] += n;
        __syncthreads();
    }
    if (t < SCAN_NB) partials[t] = s[t] - v;   // exclusive
}

// stage 3: in-block exclusive scan + global offset -> rs, cursor
__global__ void scan_blocks_kernel(const int* __restrict__ deg, const int* __restrict__ partials,
                                   int* __restrict__ rs, int* __restrict__ cursor) {
    int i = blockIdx.x * 256 + threadIdx.x;
    int lane = threadIdx.x & 63, w = threadIdx.x >> 6;
    int v = (i < NNODES) ? deg[i] : 0;
    int x = v;
#pragma unroll
    for (int o = 1; o < 64; o <<= 1) {
        int n = __shfl_up(x, o);
        if (lane >= o) x += n;
    }
    __shared__ int ws[4];
    if (lane == 63) ws[w] = x;
    __syncthreads();
    if (threadIdx.x == 0) {
        int a = 0;
#pragma unroll
        for (int k = 0; k < 4; ++k) { int t = ws[k]; ws[k] = a; a += t; }
    }
    __syncthreads();
    int excl = (x - v) + ws[w] + partials[blockIdx.x];
    if (i < NNODES) { rs[i] = excl; cursor[i] = excl; }
    if (i == 0) rs[NNODES] = NEDGES;
}

__global__ void csr_scatter_kernel(const int* __restrict__ src, const int* __restrict__ dst,
                                   int* __restrict__ cursor, int* __restrict__ csrc) {
    int e = blockIdx.x * 256 + threadIdx.x;
    if (e < NEDGES) {
        int p = atomicAdd(&cursor[dst[e]], 1);
        csrc[p] = src[e];
    }
}

// ---------- fused GIN aggregation: xb[i] = bf16(h[i] + sum_{j->i} h[j]) ----------

__global__ __launch_bounds__(256)
void gin_agg_kernel(const float* __restrict__ h, const int* __restrict__ rs,
                    const int* __restrict__ csrc, ushort* __restrict__ xb) {
    int slot = threadIdx.x >> 5;           // 8 nodes per block
    int j = threadIdx.x & 31;              // float4 lane within row
    int node = blockIdx.x * 8 + slot;
    if (node >= NNODES) return;
    int s = rs[node], e = rs[node + 1];
    float4 acc = ((const float4*)h)[(size_t)node * 32 + j];
    for (int k = s; k < e; ++k) {
        int sn = csrc[k];
        float4 v = ((const float4*)h)[(size_t)sn * 32 + j];
        acc.x += v.x; acc.y += v.y; acc.z += v.z; acc.w += v.w;
    }
    ushort4 u;
    u.x = f2b(acc.x); u.y = f2b(acc.y); u.z = f2b(acc.z); u.w = f2b(acc.w);
    ((ushort4*)xb)[(size_t)node * 32 + j] = u;
}

// ---------- fused MLP: out = (relu(A@W1+b1))@W2 + b2, + BN column stats ----------
// A: [NPAD][128] bf16. W1: [256][128] bf16 (n-major). W2: [128][256] bf16 (n-major).
// 512 threads = 8 waves (2m x 4n). 128-row block. mid tile lives in LDS only.
__global__ __launch_bounds__(512)
void fused_mlp_kernel(const ushort* __restrict__ A, const ushort* __restrict__ W1,
                      const float* __restrict__ b1, const ushort* __restrict__ W2,
                      const float* __restrict__ b2, float* __restrict__ out_f,
                      float* __restrict__ stat_sum, float* __restrict__ stat_sq) {
    __shared__ __align__(16) ushort lA[4096];     // [q][row][8], one 32-wide K step
    __shared__ __align__(16) ushort mid[32768];   // [g2=k/8][row][8]  (phase-2 A layout)
    const int tid = threadIdx.x;
    const int lane = tid & 63, wid = tid >> 6;
    const int wm = wid >> 2, wn = wid & 3;        // 2 x 4 wave grid
    const int q = lane >> 4, l16 = lane & 15;
    const int rb = blockIdx.x * 128;

    // ---- phase 1: C1[128][256] = relu(A@W1 + b1), kept in acc regs ----
    f32x4 acc1[4][4] = {};
#pragma unroll
    for (int ks = 0; ks < 4; ++ks) {
        __syncthreads();
        {
            int r0 = tid & 127, q0 = tid >> 7;    // 512 threads cover [q][row]
            bf16x8 va = *(const bf16x8*)(A + (size_t)(rb + r0) * 128 + ks * 32 + q0 * 8);
            *(bf16x8*)&lA[q0 * 1024 + r0 * 8] = va;
        }
        __syncthreads();
        bf16x8 af[4], bw[4];
#pragma unroll
        for (int mi = 0; mi < 4; ++mi)
            af[mi] = *(const bf16x8*)&lA[q * 1024 + (wm * 64 + mi * 16 + l16) * 8];
#pragma unroll
        for (int ni = 0; ni < 4; ++ni)
            bw[ni] = *(const bf16x8*)(W1 + (size_t)(wn * 64 + ni * 16 + l16) * 128 + ks * 32 + q * 8);
#pragma unroll
        for (int mi = 0; mi < 4; ++mi)
#pragma unroll
            for (int ni = 0; ni < 4; ++ni)
                acc1[mi][ni] = __builtin_amdgcn_mfma_f32_16x16x32_bf16(af[mi], bw[ni], acc1[mi][ni], 0, 0, 0);
    }

    // write relu(C1 + b1) into mid (bf16) in phase-2 A-fragment layout
#pragma unroll
    for (int ni = 0; ni < 4; ++ni) {
        int col = wn * 64 + ni * 16 + l16;        // phase-2 k index, 0..255
        float bs = b1[col];
        int g2 = col >> 3, j = col & 7;
#pragma unroll
        for (int mi = 0; mi < 4; ++mi) {
            int rowb = wm * 64 + mi * 16 + q * 4;
#pragma unroll
            for (int r = 0; r < 4; ++r) {
                float v = acc1[mi][ni][r] + bs;
                v = v > 0.f ? v : 0.f;
                mid[g2 * 1024 + (rowb + r) * 8 + j] = f2b(v);
            }
        }
    }
    __syncthreads();

    // ---- phase 2: C2[128][128] = mid@W2 + b2, store f32 + BN stats ----
    f32x4 acc2[4][2] = {};
#pragma unroll
    for (int ks = 0; ks < 8; ++ks) {
        bf16x8 af[4], bw[2];
#pragma unroll
        for (int mi = 0; mi < 4; ++mi)
            af[mi] = *(const bf16x8*)&mid[(ks * 4 + q) * 1024 + (wm * 64 + mi * 16 + l16) * 8];
#pragma unroll
        for (int ni = 0; ni < 2; ++ni)
            bw[ni] = *(const bf16x8*)(W2 + (size_t)(wn * 32 + ni * 16 + l16) * 256 + ks * 32 + q * 8);
#pragma unroll
        for (int mi = 0; mi < 4; ++mi)
#pragma unroll
            for (int ni = 0; ni < 2; ++ni)
                acc2[mi][ni] = __builtin_amdgcn_mfma_f32_16x16x32_bf16(af[mi], bw[ni], acc2[mi][ni], 0, 0, 0);
    }

#pragma unroll
    for (int ni = 0; ni < 2; ++ni) {
        int col = wn * 32 + ni * 16 + l16;
        float bs = b2[col];
        float s = 0.f, sq = 0.f;
#pragma unroll
        for (int mi = 0; mi < 4; ++mi) {
            int row = rb + wm * 64 + mi * 16 + q * 4;
#pragma unroll
            for (int r = 0; r < 4; ++r) {
                float v = acc2[mi][ni][r] + bs;
                out_f[(size_t)(row + r) * 128 + col] = v;
                if (row + r < NNODES) { s += v; sq += v * v; }
            }
        }
        s  += __shfl_xor(s, 16);  s  += __shfl_xor(s, 32);
        sq += __shfl_xor(sq, 16); sq += __shfl_xor(sq, 32);
        if (lane < 16) {
            atomicAdd(&stat_sum[col], s);
            atomicAdd(&stat_sq[col], sq);
        }
    }
}

__global__ void bn_finalize_kernel(const float* __restrict__ sum, const float* __restrict__ sq,
                                   const float* __restrict__ g, const float* __restrict__ b,
                                   float* __restrict__ scale, float* __restrict__ shift) {
    int d = threadIdx.x;
    float mu = sum[d] * (1.f / NNODES);
    float var = sq[d] * (1.f / NNODES) - mu * mu;
    var = var < 0.f ? 0.f : var;
    float sc = g[d] * rsqrtf(var + 1e-5f);
    scale[d] = sc;
    shift[d] = b[d] - mu * sc;
}

__global__ void bn_apply_kernel(const float* __restrict__ m, const float* __restrict__ scale,
                                const float* __restrict__ shift, float* __restrict__ h, int resid) {
    int t = blockIdx.x * 256 + threadIdx.x;   // NNODES*32 float4 units
    if (t >= NNODES * 32) return;
    int j = t & 31;
    float4 mm = ((const float4*)m)[t];
    float4 sc = ((const float4*)scale)[j];
    float4 sh = ((const float4*)shift)[j];
    float4 v;
    v.x = fmaxf(mm.x * sc.x + sh.x, 0.f);
    v.y = fmaxf(mm.y * sc.y + sh.y, 0.f);
    v.z = fmaxf(mm.z * sc.z + sh.z, 0.f);
    v.w = fmaxf(mm.w * sc.w + sh.w, 0.f);
    if (resid) {
        float4 hp = ((const float4*)h)[t];
        v.x += hp.x; v.y += hp.y; v.z += hp.z; v.w += hp.w;
    }
    ((float4*)h)[t] = v;
}

__device__ __forceinline__ int lbound(const int* __restrict__ b, int key) {
    int lo = 0, hi = NNODES;
    while (lo < hi) { int m = (lo + hi) >> 1; if (b[m] < key) lo = m + 1; else hi = m; }
    return lo;
}

__global__ void pool_kernel(const float* __restrict__ h, const int* __restrict__ batch,
                            float* __restrict__ out) {
    int g = blockIdx.x;
    int d = threadIdx.x & 127, hh = threadIdx.x >> 7;
    int s = lbound(batch, g), e = lbound(batch, g + 1);
    float acc = 0.f;
    for (int r = s + hh; r < e; r += 2) acc += h[(size_t)r * 128 + d];
    __shared__ float buf[128];
    if (hh) buf[d] = acc;
    __syncthreads();
    if (!hh) {
        float tot = acc + buf[d];
        int c = e - s;
        out[g * 128 + d] = tot / (float)(c > 0 ? c : 1);
    }
}

__global__ void vn_update_kernel(const float* __restrict__ tmp, const float* __restrict__ W1,
                                 const float* __restrict__ b1, const float* __restrict__ W2,
                                 const float* __restrict__ b2, float* __restrict__ vn) {
    __shared__ float t[128], t1[128];
    int g = blockIdx.x, d = threadIdx.x;
    t[d] = tmp[g * 128 + d];
    __syncthreads();
    float a = b1[d];
    for (int k = 0; k < 128; ++k) a += t[k] * W1[k * 128 + d];
    t1[d] = fmaxf(a, 0.f);
    __syncthreads();
    float o = b2[d];
    for (int k = 0; k < 128; ++k) o += t1[k] * W2[k * 128 + d];
    vn[g * 128 + d] += o;
}

__global__ void add_vn_kernel(const float* __restrict__ h, const float* __restrict__ vn,
                              const int* __restrict__ batch, float* __restrict__ outp) {
    int t = blockIdx.x * 256 + threadIdx.x;   // NNODES*32
    if (t >= NNODES * 32) return;
    int row = t >> 5, j = t & 31;
    int g = batch[row];
    float4 a = ((const float4*)h)[t];
    float4 b = ((const float4*)vn)[(size_t)g * 32 + j];
    a.x += b.x; a.y += b.y; a.z += b.z; a.w += b.w;
    ((float4*)outp)[t] = a;
}

__global__ void graph_mlp_kernel(const float* __restrict__ gf, const float* __restrict__ W1,
                                 const float* __restrict__ b1, const float* __restrict__ lng,
                                 const float* __restrict__ lnb, const float* __restrict__ W2,
                                 const float* __restrict__ b2, float* __restrict__ out) {
    __shared__ float t[128], t1[128], red[2];
    int g = blockIdx.x, d = threadIdx.x;
    int lane = d & 63, w = d >> 6;
    t[d] = gf[g * 128 + d];
    __syncthreads();
    float a = b1[d];
    for (int k = 0; k < 128; ++k) a += t[k] * W1[k * 128 + d];
    float s = a;
#pragma unroll
    for (int o = 1; o < 64; o <<= 1) s += __shfl_xor(s, o);
    if (lane == 0) red[w] = s;
    __syncthreads();
    float mu = (red[0] + red[1]) * (1.f / 128.f);
    float dv = a - mu;
    float qq = dv * dv;
#pragma unroll
    for (int o = 1; o < 64; o <<= 1) qq += __shfl_xor(qq, o);
    __syncthreads();
    if (lane == 0) red[w] = qq;
    __syncthreads();
    float var = (red[0] + red[1]) * (1.f / 128.f);
    float v = dv * rsqrtf(var + 1e-5f) * lng[d] + lnb[d];
    v = fmaxf(v, 0.f);
    t1[d] = v;
    __syncthreads();
    float o2 = b2[d];
    for (int k = 0; k < 128; ++k) o2 += t1[k] * W2[k * 128 + d];
    out[g * 128 + d] = o2;
}

extern "C" void kernel_launch(void* const* d_in, const int* in_sizes, int n_in,
                              void* d_out, int out_size, void* d_ws, size_t ws_size,
                              hipStream_t stream) {
    const float* x    = (const float*)d_in[0];
    const int*   edge = (const int*)d_in[1];
    const int*   src  = edge;
    const int*   dst  = edge + NEDGES;
    const int*   batch = (const int*)d_in[2];
    const float* nW   = (const float*)d_in[3];
    const float* nb   = (const float*)d_in[4];
    const float* W1s  = (const float*)d_in[5];
    const float* b1s  = (const float*)d_in[6];
    const float* W2s  = (const float*)d_in[7];
    const float* b2s  = (const float*)d_in[8];
    const float* bng  = (const float*)d_in[9];
    const float* bnb  = (const float*)d_in[10];
    const float* vne  = (const float*)d_in[11];
    const float* vW1  = (const float*)d_in[12];
    const float* vb1  = (const float*)d_in[13];
    const float* vW2  = (const float*)d_in[14];
    const float* vb2  = (const float*)d_in[15];
    const float* gW1  = (const float*)d_in[16];
    const float* gb1  = (const float*)d_in[17];
    const float* lng  = (const float*)d_in[18];
    const float* lnb  = (const float*)d_in[19];
    const float* gW2  = (const float*)d_in[20];
    const float* gb2  = (const float*)d_in[21];

    char* ws = (char*)d_ws;
    auto alloc = [&](size_t bytes) { char* p = ws; ws += (bytes + 255) & ~(size_t)255; return p; };
    float*  hf    = (float*)alloc((size_t)NPAD * 128 * 4);
    float*  mbuf  = (float*)alloc((size_t)NPAD * 128 * 4);
    ushort* xb    = (ushort*)alloc((size_t)NPAD * 128 * 2);
    float*  vn    = (float*)alloc((size_t)NGRAPH * 128 * 4);
    float*  tmp   = (float*)alloc((size_t)NGRAPH * 128 * 4);
    ushort* w1t   = (ushort*)alloc((size_t)NLAYER * 256 * 128 * 2);
    ushort* w2t   = (ushort*)alloc((size_t)NLAYER * 128 * 256 * 2);
    float*  stats = (float*)alloc(256 * 4);
    float*  scale = (float*)alloc(128 * 4);
    float*  shift = (float*)alloc(128 * 4);
    int*    deg   = (int*)alloc((size_t)NNODES * 4);
    int*    rs    = (int*)alloc((size_t)(NNODES + 1) * 4);
    int*    cursor= (int*)alloc((size_t)NNODES * 4);
    int*    csrc  = (int*)alloc((size_t)NEDGES * 4);
    int*    partials = (int*)alloc((size_t)SCAN_NB * 4);
    float*  colsum = stats;
    float*  colsq  = stats + 128;

    float* outN = (float*)d_out;
    float* outG = outN + (size_t)NNODES * 128;

    // CSR build (edges constant across layers)
    hipMemsetAsync(deg, 0, (size_t)NNODES * 4, stream);
    deg_kernel<<<(NEDGES + 255) / 256, 256, 0, stream>>>(dst, deg);
    scan_part_kernel<<<SCAN_NB, 256, 0, stream>>>(deg, partials);
    scan_top_kernel<<<1, 512, 0, stream>>>(partials);
    scan_blocks_kernel<<<SCAN_NB, 256, 0, stream>>>(deg, partials, rs, cursor);
    csr_scatter_kernel<<<(NEDGES + 255) / 256, 256, 0, stream>>>(src, dst, cursor, csrc);

    prep_w_kernel<<<(2 * NLAYER * 128 * 256 + 255) / 256, 256, 0, stream>>>(W1s, W2s, w1t, w2t);
    node_embed_kernel<<<(NNODES * 128 + 255) / 256, 256, 0, stream>>>(x, nW, nb, hf);
    vn_init_kernel<<<(NGRAPH * 128 + 255) / 256, 256, 0, stream>>>(vne, vn);

    for (int i = 0; i < NLAYER; ++i) {
        gin_agg_kernel<<<(NNODES + 7) / 8, 256, 0, stream>>>(hf, rs, csrc, xb);
        hipMemsetAsync(stats, 0, 256 * 4, stream);
        fused_mlp_kernel<<<NPAD / 128, 512, 0, stream>>>(
            xb, w1t + (size_t)i * 256 * 128, b1s + i * 256,
            w2t + (size_t)i * 128 * 256, b2s + i * 128, mbuf, colsum, colsq);
        bn_finalize_kernel<<<1, 128, 0, stream>>>(colsum, colsq, bng + i * 128, bnb + i * 128, scale, shift);
        bn_apply_kernel<<<(NNODES * 32 + 255) / 256, 256, 0, stream>>>(mbuf, scale, shift, hf, i > 0 ? 1 : 0);
        pool_kernel<<<NGRAPH, 256, 0, stream>>>(hf, batch, tmp);
        vn_update_kernel<<<NGRAPH, 128, 0, stream>>>(tmp, vW1, vb1, vW2, vb2, vn);
        add_vn_kernel<<<(NNODES * 32 + 255) / 256, 256, 0, stream>>>(
            hf, vn, batch, (i == NLAYER - 1) ? outN : hf);
    }
    pool_kernel<<<NGRAPH, 256, 0, stream>>>(outN, batch, tmp);
    graph_mlp_kernel<<<NGRAPH, 128, 0, stream>>>(tmp, gW1, gb1, lng, lnb, gW2, gb2, outG);
}